// Round 17
// baseline (312.837 us; speedup 1.0000x reference)
//
#include <hip/hip_runtime.h>
#include <hip/hip_bf16.h>

typedef __hip_bfloat16 bf16;
typedef __attribute__((ext_vector_type(8))) short short8;
typedef __attribute__((ext_vector_type(16))) float float16v;
typedef __attribute__((ext_vector_type(2))) float float2v;

#define B_     16
#define N_     48
#define NODES  768
#define PAIRS  2256
#define EK     36096
#define S_     2256
#define SH     1128
#define D_     192
#define KITERS 71
#define QTILES 71
#define KPB    6144   // K' elements per (batch,tile): 12*2*32*8
#define QSCALE 0.10411754f  // log2(e)/sqrt(192): folded into Q at store

__device__ __forceinline__ float bf(const bf16* p, int i) { return __bfloat162float(p[i]); }
__device__ __forceinline__ float u2f(unsigned short u) {
    return __uint_as_float(((unsigned int)u) << 16);
}
__device__ __forceinline__ float sanitize(float v) {
    if (v > -1e4f && v < 1e4f) return v;
    if (v >= 1e4f) return 1e4f;
    if (v <= -1e4f) return -1e4f;
    return 0.f;  // NaN
}

// ============ STAGE 1: graphconv (blocks 0..15) | compose_a1 (16..208) |
// ============          compose_b (209..496)  — mutually independent ============
__global__ __launch_bounds__(256) void stage1_kernel(
    const bf16* edge_attr, const bf16* W_we, const bf16* b_we, const bf16* x,
    const bf16* Wrel1, const bf16* brel1, const bf16* Wroot1,
    const bf16* Wrel2, const bf16* brel2, const bf16* Wroot2,
    const bf16* W_o, const bf16* b_o, const bf16* W_out, const bf16* b_out,
    const bf16* W_in, const bf16* b_in, const bf16* b_qkv, const bf16* W_qkv,
    float* x2out, float* wo_eff, float* bq_eff, float* bk_eff, float* bv_eff, float* sc,
    float* WqT, float* WkT, bf16* W2b) {
    int blk = blockIdx.x, tid = threadIdx.x;
    if (blk < 16) {  // ---- graphconv, one block per batch ----
        int b = blk;
        __shared__ float s_ws[N_ * N_];
        __shared__ float s_x[N_ * 5], s_agg1[N_ * 5];
        __shared__ float s_x1[N_ * 32], s_agg2[N_ * 32];
        float we0 = bf(W_we, 0), we1 = bf(W_we, 1), we2 = bf(W_we, 2), bw = bf(b_we, 0);
        for (int idx = tid; idx < N_ * N_; idx += 256) {
            int i = idx / N_, j = idx % N_;
            float v = 0.f;
            if (i != j) {
                int p = i * 47 + (j < i ? j : j - 1);
                int e = (b * PAIRS + p) * 2;
                float w0 = fmaxf(we0 * bf(edge_attr, (e + 0) * 2) + we1 + bw, 0.f);
                float w1 = fmaxf(we0 * bf(edge_attr, (e + 1) * 2) + we2 + bw, 0.f);
                v = w0 + w1;
            }
            s_ws[idx] = v;
        }
        for (int idx = tid; idx < N_ * 5; idx += 256) s_x[idx] = bf(x, b * N_ * 5 + idx);
        __syncthreads();
        if (tid < 240) {
            int j = tid / 5, f = tid % 5;
            float a = 0.f;
            for (int i = 0; i < N_; i++) a += s_ws[i * N_ + j] * s_x[i * 5 + f];
            s_agg1[tid] = a;
        }
        __syncthreads();
        for (int o = tid; o < N_ * 32; o += 256) {
            int j = o >> 5, h = o & 31;
            float a = bf(brel1, h);
            for (int f = 0; f < 5; f++)
                a += bf(Wrel1, h * 5 + f) * s_agg1[j * 5 + f] +
                     bf(Wroot1, h * 5 + f) * s_x[j * 5 + f];
            s_x1[o] = fmaxf(a, 0.f);
        }
        __syncthreads();
        for (int o = tid; o < N_ * 32; o += 256) {
            int j = o >> 5, h = o & 31;
            float a = 0.f;
            for (int i = 0; i < N_; i++) a += s_ws[i * N_ + j] * s_x1[i * 32 + h];
            s_agg2[o] = a;
        }
        __syncthreads();
        for (int o = tid; o < N_ * 64; o += 256) {
            int j = o >> 6, h2 = o & 63;
            float a = bf(brel2, h2);
            for (int h1 = 0; h1 < 32; h1++)
                a += bf(Wrel2, h2 * 32 + h1) * s_agg2[j * 32 + h1] +
                     bf(Wroot2, h2 * 32 + h1) * s_x1[j * 32 + h1];
            x2out[(b * N_ + j) * 64 + h2] = fmaxf(a, 0.f);
        }
    } else if (blk < 209) {  // ---- compose_a1 ----
        int a = blk - 16;  // 0..191 outputs; 192 = co
        int wave = tid >> 6, lane = tid & 63;
        float partial = 0.f;
        if (a < 192) {
            if (wave == 0) {
                for (int m = lane; m < 192; m += 64)
                    partial += bf(W_o, m) * bf(W_out, m * 192 + a);
            } else {
                int row = (wave - 1) * 192 + a;
                for (int m = lane; m < 192; m += 64)
                    partial += bf(W_in, row * 192 + m) * bf(b_qkv, (wave - 1) * 192 + m);
            }
        } else if (wave == 0) {
            for (int m = lane; m < 192; m += 64) partial += bf(W_o, m) * bf(b_out, m);
        }
        for (int off = 32; off; off >>= 1) partial += __shfl_xor(partial, off, 64);
        if (lane == 0) {
            if (a < 192) {
                if (wave == 0) wo_eff[a] = partial;
                else if (wave == 1) bq_eff[a] = partial + bf(b_in, a);
                else if (wave == 2) bk_eff[a] = partial + bf(b_in, 192 + a);
                else bv_eff[a] = partial + bf(b_in, 384 + a);
            } else if (wave == 0) sc[1] = partial + bf(b_o, 0);
        }
    } else {  // ---- compose_b: Wq/Wk transposed tables + W2b bf16 ----
        int idx = (blk - 209) * 256 + tid;  // 0 .. 2*D*D-1
        if (idx < D_ * D_) {
            int a = idx / D_, c = idx % D_;
            float acc = 0.f;
            for (int m = 0; m < D_; m++) acc += bf(W_in, a * D_ + m) * bf(W_qkv, m * D_ + c);
            WqT[c * D_ + a] = acc;
            if (c >= 64 && c < 128) W2b[a * 64 + (c - 64)] = __float2bfloat16(acc);
        } else {
            int t = idx - D_ * D_, a = t / D_, c = t % D_;
            float acc = 0.f;
            for (int m = 0; m < D_; m++)
                acc += bf(W_in, (D_ + a) * D_ + m) * bf(W_qkv, (D_ + m) * D_ + c);
            WkT[c * D_ + a] = acc;
            if (c >= 64 && c < 128) W2b[(192 + a) * 64 + (c - 64)] = __float2bfloat16(acc);
        }
    }
}

// ============ STAGE 2: sc0 (block 0) | wvl quadratic (1..192) | nodeproj (193..960) ====
__global__ __launch_bounds__(256) void stage2_kernel(
    const bf16* W_in, const bf16* W_qkv, const float* wo_eff, const float* bv_eff,
    const float* x2, const float* WqT, const float* WkT,
    const float* bq_eff, const float* bk_eff,
    float* wvl, float* sc, float* Tq1, float* Tq3, float* Tk1, float* Tk3) {
    int blk = blockIdx.x, tid = threadIdx.x;
    if (blk == 0) {
        if (tid < 64) {
            float partial = 0.f;
            for (int aa = tid; aa < 192; aa += 64) partial += wo_eff[aa] * bv_eff[aa];
            for (int off = 32; off; off >>= 1) partial += __shfl_xor(partial, off, 64);
            if (tid == 0) sc[0] = partial;
        }
    } else if (blk < 193) {
        int w = blk - 1;
        __shared__ float s_tm[192];
        if (tid < 192) {
            float tm = 0.f;
            for (int aa = 0; aa < 192; aa++)
                tm += wo_eff[aa] * bf(W_in, (384 + aa) * 192 + tid);
            s_tm[tid] = tm;
        }
        __syncthreads();
        if (tid < 64) {
            float partial = 0.f;
            for (int m = tid; m < 192; m += 64)
                partial += s_tm[m] * bf(W_qkv, (384 + m) * 192 + w);
            for (int off = 32; off; off >>= 1) partial += __shfl_xor(partial, off, 64);
            if (tid == 0) wvl[w] = partial;
        }
    } else {
        int n = blk - 193;
        __shared__ float sx[64];
        if (tid < 64) sx[tid] = x2[n * 64 + tid];
        __syncthreads();
        if (tid < D_) {
            int a = tid;
            float q1 = bq_eff[a], q3 = 0.f, k1 = bk_eff[a], k3 = 0.f;
            for (int c = 0; c < 64; c++) {
                float xv = sx[c];
                q1 += WqT[c * D_ + a] * xv;
                q3 += WqT[(128 + c) * D_ + a] * xv;
                k1 += WkT[c * D_ + a] * xv;
                k3 += WkT[(128 + c) * D_ + a] * xv;
            }
            Tq1[n * D_ + a] = q1; Tq3[n * D_ + a] = q3;
            Tk1[n * D_ + a] = k1; Tk3[n * D_ + a] = k3;
        }
    }
}

// ============ K3: MFMA per-edge mid-GEMM — writes K in MFMA-B-permuted layout ========
__global__ __launch_bounds__(256) void qkvmid_kernel(
    const bf16* edge_attr, const bf16* W_ee, const bf16* b_ee, const bf16* W2b,
    const float* wvl, const float* sc, const float* x2,
    const float* Tq1, const float* Tq3, const float* Tk1, const float* Tk3,
    bf16* Q, bf16* Kp, float* vl) {
    __shared__ short s_wk[32 * 72];
    __shared__ float s_wvl[192];
    __shared__ int s_ni[32], s_nj[32], s_koff[32];
    __shared__ float s_wraw[32], s_cls[32];
    int tid = threadIdx.x, base = blockIdx.x * 32;
    int wave = tid >> 6, lane = tid & 63;
    int l5 = lane & 31, h5 = lane >> 5;

    short8 bfr[3][4];
    #pragma unroll
    for (int tt = 0; tt < 3; tt++) {
        int ta = wave + tt * 4;
        const short* wrow = (const short*)W2b + (ta * 32 + l5) * 64;
        #pragma unroll
        for (int kc = 0; kc < 4; kc++)
            bfr[tt][kc] = *(const short8*)(wrow + kc * 16 + h5 * 8);
    }

    if (tid < 192) s_wvl[tid] = wvl[tid];
    if (tid < 32) {
        int kk_g = base + tid;
        int b = kk_g / S_, kk = kk_g % S_;
        int q = kk >> 1, cls = kk & 1;
        int i = (int)((1.0f + sqrtf(8.0f * (float)q + 1.0f)) * 0.5f);
        while (i * (i - 1) / 2 > q) --i;
        while ((i + 1) * i / 2 <= q) ++i;
        int j = q - i * (i - 1) / 2;
        s_ni[tid] = b * N_ + i; s_nj[tid] = b * N_ + j;
        int e = (b * PAIRS + i * 47 + j) * 2 + cls;
        s_wraw[tid] = bf(edge_attr, e * 2);
        s_cls[tid] = (float)cls;
        s_koff[tid] = (b * KITERS + (kk >> 5)) * KPB + (kk & 31) * 8;
    }
    __syncthreads();
    for (int idx = tid; idx < 32 * 64; idx += 256) {
        int t = idx >> 6, h = idx & 63;
        int cls = (int)s_cls[t];
        float v = bf(W_ee, h * 3) * s_wraw[t] + bf(W_ee, h * 3 + 1 + cls) + bf(b_ee, h);
        bf16 bv = __float2bfloat16(fmaxf(v, 0.f));
        s_wk[t * 72 + h] = *reinterpret_cast<short*>(&bv);
    }
    __syncthreads();

    short8 af[4];
    #pragma unroll
    for (int kc = 0; kc < 4; kc++)
        af[kc] = *(const short8*)&s_wk[l5 * 72 + kc * 16 + h5 * 8];

    int tl[16], niv[16], njv[16];
    #pragma unroll
    for (int r = 0; r < 16; r++) {
        int t = (r & 3) + 8 * (r >> 2) + 4 * h5;
        tl[r] = t; niv[r] = s_ni[t]; njv[r] = s_nj[t];
    }

    #pragma unroll
    for (int tt = 0; tt < 3; tt++) {
        int ta = wave + tt * 4;
        bool isq = ta < 6;
        int ag = (isq ? ta : ta - 6) * 32 + l5;
        float16v c;
        #pragma unroll
        for (int r = 0; r < 16; r++) c[r] = 0.f;
        #pragma unroll
        for (int kc = 0; kc < 4; kc++)
            c = __builtin_amdgcn_mfma_f32_32x32x16_bf16(af[kc], bfr[tt][kc], c, 0, 0, 0);
        const float* T1 = isq ? Tq1 : Tk1;
        const float* T3 = isq ? Tq3 : Tk3;
        if (isq) {
            #pragma unroll
            for (int r = 0; r < 16; r++) {
                float v = (c[r] + T1[niv[r] * D_ + ag] + T3[njv[r] * D_ + ag]) * QSCALE;
                Q[(long)(base + tl[r]) * D_ + ag] = __float2bfloat16(v);
            }
        } else {
            int kc = ag >> 4, h5w = (ag >> 3) & 1, e = ag & 7;
            int coff = kc * 512 + h5w * 256 + e;
            #pragma unroll
            for (int r = 0; r < 16; r++) {
                float v = c[r] + T1[niv[r] * D_ + ag] + T3[njv[r] * D_ + ag];
                Kp[s_koff[tl[r]] + coff] = __float2bfloat16(v);
            }
        }
    }
    {
        int t = tid >> 3, g = tid & 7;
        const float* xi = &x2[s_ni[t] * 64];
        const float* xj = &x2[s_nj[t] * 64];
        float v = 0.f;
        #pragma unroll
        for (int hh = 0; hh < 8; hh++) {
            int h = g * 8 + hh;
            v += s_wvl[h] * xi[h] + s_wvl[128 + h] * xj[h] +
                 s_wvl[64 + h] * u2f((unsigned short)s_wk[t * 72 + h]);
        }
        v += __shfl_xor(v, 1, 64);
        v += __shfl_xor(v, 2, 64);
        v += __shfl_xor(v, 4, 64);
        if (g == 0) vl[base + t] = v + sc[0];
    }
}

// ============ K4: attn — permuted-K, barrier-free, 2 q-tiles/wave, half-K split ======
__global__ __launch_bounds__(256) void attn_kernel(const bf16* Q, const bf16* Kp,
                                                   const float* vl, float* part,
                                                   int chunk0) {
    // 576 blocks = 8 XCDs x (2 batches x 4 chunks x 9 q-groups); 4 waves x 2 q-tiles
    int x = blockIdx.x;
    int rr = x & 7, rest = x >> 3;       // rest 0..71
    int hi = rest >= 36;
    int b = rr + 8 * hi;
    int s = rest - 36 * hi;              // 0..35
    int chunk = chunk0 + s / 9, qg = s % 9;
    int tid = threadIdx.x;
    int wave = tid >> 6, lane = tid & 63;
    int n5 = lane & 31, h5 = lane >> 5;
    int qtA = qg * 8 + wave * 2;         // 0..70 even — always valid
    int qtB = qtA + 1;                   // 1..71 (71 invalid)
    bool validB = qtB < QTILES;
    int t0 = chunk * 9;
    int nit = (chunk == 7) ? 8 : 9;

    short8 qfA[12], qfB[12];
    {
        int qrowA = b * S_ + qtA * 32 + n5;
        int qrowB = b * S_ + qtB * 32 + n5;
        if (qrowB > B_ * S_ - 1) qrowB = B_ * S_ - 1;
        const short* qpA = (const short*)Q + (long)qrowA * D_;
        const short* qpB = (const short*)Q + (long)qrowB * D_;
        #pragma unroll
        for (int kc = 0; kc < 12; kc++) {
            qfA[kc] = *(const short8*)(qpA + kc * 16 + h5 * 8);
            qfB[kc] = *(const short8*)(qpB + kc * 16 + h5 * 8);
        }
    }

    float lrA[16], arA[16], lrB[16], arB[16];
    #pragma unroll
    for (int r = 0; r < 16; r++) { lrA[r] = 0.f; arA[r] = 0.f; lrB[r] = 0.f; arB[r] = 0.f; }

    const short* Kb = (const short*)Kp + (long)b * KITERS * KPB + h5 * 256 + n5 * 8;
    const float* vlb = vl + b * S_;

    for (int k = 0; k < nit; ++k) {
        int it = t0 + k;
        const short* kp = Kb + it * KPB;
        int row = it * 32 + n5;
        float vlv = vlb[row < S_ ? row : S_ - 1];
        float16v cA, cB;
        #pragma unroll
        for (int r = 0; r < 16; r++) { cA[r] = 0.f; cB[r] = 0.f; }
        #pragma unroll
        for (int kc = 0; kc < 12; kc++) {           // rolling B-frag: load once, 2 MFMAs
            short8 bfr = *(const short8*)(kp + kc * 512);
            cA = __builtin_amdgcn_mfma_f32_32x32x16_bf16(qfA[kc], bfr, cA, 0, 0, 0);
            cB = __builtin_amdgcn_mfma_f32_32x32x16_bf16(qfB[kc], bfr, cB, 0, 0, 0);
        }
        if (it != KITERS - 1) {
            #pragma unroll
            for (int r = 0; r < 16; r++) {
                float pA = __builtin_amdgcn_exp2f(cA[r]);
                float pB = __builtin_amdgcn_exp2f(cB[r]);
                lrA[r] += pA; arA[r] += pA * vlv;
                lrB[r] += pB; arB[r] += pB * vlv;
            }
        } else {
            bool kv = n5 < 16;
            #pragma unroll
            for (int r = 0; r < 16; r++) {
                float pA = kv ? __builtin_amdgcn_exp2f(cA[r]) : 0.f;
                float pB = kv ? __builtin_amdgcn_exp2f(cB[r]) : 0.f;
                lrA[r] += pA; arA[r] += pA * vlv;
                lrB[r] += pB; arB[r] += pB * vlv;
            }
        }
    }

    #pragma unroll
    for (int r = 0; r < 16; r++) {
        float l = lrA[r], a = arA[r];
        #pragma unroll
        for (int off = 1; off < 32; off <<= 1) {
            l += __shfl_xor(l, off, 64);
            a += __shfl_xor(a, off, 64);
        }
        if (n5 == 0) {
            int qrow = qtA * 32 + (r & 3) + 8 * (r >> 2) + 4 * h5;
            float2v pv2 = {l, a};
            *(float2v*)&part[((long)(b * S_ + qrow) * 8 + chunk) * 2] = pv2;
        }
    }
    if (validB) {
        #pragma unroll
        for (int r = 0; r < 16; r++) {
            float l = lrB[r], a = arB[r];
            #pragma unroll
            for (int off = 1; off < 32; off <<= 1) {
                l += __shfl_xor(l, off, 64);
                a += __shfl_xor(a, off, 64);
            }
            if (n5 == 0) {
                int qrow = qtB * 32 + (r & 3) + 8 * (r >> 2) + 4 * h5;
                if (qrow < S_) {
                    float2v pv2 = {l, a};
                    *(float2v*)&part[((long)(b * S_ + qrow) * 8 + chunk) * 2] = pv2;
                }
            }
        }
    }
}

// ============ K5: merge partials + pairing/argmin ============
__global__ __launch_bounds__(256) void final_kernel(const float* part, const float* sc,
                                                    float* out) {
    int idx = blockIdx.x * 256 + threadIdx.x;
    if (idx >= B_ * SH) return;
    int b = idx / SH, p = idx % SH;
    int i = (int)((1.0f + sqrtf(8.0f * (float)p + 1.0f)) * 0.5f);
    while (i * (i - 1) / 2 > p) --i;
    while ((i + 1) * i / 2 <= p) ++i;
    int j = p - i * (i - 1) / 2;
    float co = sc[1];
    float lg[2];
    #pragma unroll
    for (int t = 0; t < 2; t++) {
        long g = (long)b * S_ + 2 * p + t;
        float l = 0.f, a = 0.f;
        #pragma unroll
        for (int c = 0; c < 8; c++) {
            float2v pc = *(const float2v*)&part[(g * 8 + c) * 2];
            l += pc.x;
            a += pc.y;
        }
        lg[t] = sanitize(a / l + co);
    }
    int ind = (lg[1] < lg[0]) ? 1 : 0;
    float ef = ind ? lg[1] : lg[0];
    out[(b * SH + p) * 2 + 0] = (float)(b * N_ + i);
    out[(b * SH + p) * 2 + 1] = (float)(b * N_ + j);
    out[2 * B_ * SH + idx] = ef;
    out[2 * B_ * SH + B_ * SH + idx] = (float)ind;
}

extern "C" void kernel_launch(void* const* d_in, const int* in_sizes, int n_in,
                              void* d_out, int out_size, void* d_ws, size_t ws_size,
                              hipStream_t stream) {
    const bf16* x         = (const bf16*)d_in[0];
    const bf16* edge_attr = (const bf16*)d_in[2];
    const bf16* W_we   = (const bf16*)d_in[5];
    const bf16* b_we   = (const bf16*)d_in[6];
    const bf16* Wrel1  = (const bf16*)d_in[7];
    const bf16* brel1  = (const bf16*)d_in[8];
    const bf16* Wroot1 = (const bf16*)d_in[9];
    const bf16* Wrel2  = (const bf16*)d_in[10];
    const bf16* brel2  = (const bf16*)d_in[11];
    const bf16* Wroot2 = (const bf16*)d_in[12];
    const bf16* W_ee   = (const bf16*)d_in[13];
    const bf16* b_ee   = (const bf16*)d_in[14];
    const bf16* W_qkv  = (const bf16*)d_in[15];
    const bf16* b_qkv  = (const bf16*)d_in[16];
    const bf16* W_in   = (const bf16*)d_in[17];
    const bf16* b_in   = (const bf16*)d_in[18];
    const bf16* W_out  = (const bf16*)d_in[19];
    const bf16* b_out  = (const bf16*)d_in[20];
    const bf16* W_o    = (const bf16*)d_in[21];
    const bf16* b_o    = (const bf16*)d_in[22];

    float* w = (float*)d_ws;
    float* WqT    = w;                  // 36864
    float* WkT    = WqT + 36864;        // 36864
    float* bq_eff = WkT + 36864;        // 192
    float* bk_eff = bq_eff + 192;
    float* bv_eff = bk_eff + 192;
    float* wo_eff = bv_eff + 192;
    float* wvl    = wo_eff + 192;       // 192
    float* sc     = wvl + 192;          // 64 (2 used)
    float* x2     = sc + 64;            // 49152
    float* vl     = x2 + 49152;         // 36096
    float* part   = vl + 36096;         // 577536
    bf16*  Q      = (bf16*)(part + 577536);     // EK*192 bf16
    bf16*  Kp     = Q + (long)EK * D_;          // 16*71*6144 bf16 (permuted)
    bf16*  W2b    = Kp + (long)B_ * KITERS * KPB;  // 384*64 bf16
    float* Tq1    = (float*)(W2b + 384 * 64);
    float* Tq3    = Tq1 + NODES * D_;
    float* Tk1    = Tq3 + NODES * D_;
    float* Tk3    = Tk1 + NODES * D_;
    // total ~36 MB of 256 MB workspace

    stage1_kernel<<<497, 256, 0, stream>>>(edge_attr, W_we, b_we, x, Wrel1, brel1, Wroot1,
                                           Wrel2, brel2, Wroot2, W_o, b_o, W_out, b_out,
                                           W_in, b_in, b_qkv, W_qkv,
                                           x2, wo_eff, bq_eff, bk_eff, bv_eff, sc,
                                           WqT, WkT, W2b);
    stage2_kernel<<<961, 256, 0, stream>>>(W_in, W_qkv, wo_eff, bv_eff, x2, WqT, WkT,
                                           bq_eff, bk_eff, wvl, sc, Tq1, Tq3, Tk1, Tk3);
    qkvmid_kernel<<<EK / 32, 256, 0, stream>>>(edge_attr, W_ee, b_ee, W2b, wvl, sc, x2,
                                               Tq1, Tq3, Tk1, Tk3, Q, Kp, vl);
    attn_kernel<<<576, 256, 0, stream>>>(Q, Kp, vl, part, 0);
    attn_kernel<<<576, 256, 0, stream>>>(Q, Kp, vl, part, 4);
    final_kernel<<<(B_ * SH + 255) / 256, 256, 0, stream>>>(part, sc, (float*)d_out);
}

// Round 18
// 293.054 us; speedup vs baseline: 1.0675x; 1.0675x over previous
//
#include <hip/hip_runtime.h>
#include <hip/hip_bf16.h>

typedef __hip_bfloat16 bf16;
typedef __attribute__((ext_vector_type(8))) short short8;
typedef __attribute__((ext_vector_type(16))) float float16v;
typedef __attribute__((ext_vector_type(2))) float float2v;

#define B_     16
#define N_     48
#define NODES  768
#define PAIRS  2256
#define EK     36096
#define S_     2256
#define SH     1128
#define D_     192
#define KITERS 71
#define QTILES 71
#define KPB    6144   // K' elements per (batch,tile): 12*2*32*8
#define QSCALE 0.10411754f  // log2(e)/sqrt(192): folded into Q at store

__device__ __forceinline__ float bf(const bf16* p, int i) { return __bfloat162float(p[i]); }
__device__ __forceinline__ float u2f(unsigned short u) {
    return __uint_as_float(((unsigned int)u) << 16);
}
__device__ __forceinline__ float sanitize(float v) {
    if (v > -1e4f && v < 1e4f) return v;
    if (v >= 1e4f) return 1e4f;
    if (v <= -1e4f) return -1e4f;
    return 0.f;  // NaN
}

// ============ STAGE 1: graphconv (blocks 0..15) | compose_a1 (16..208) |
// ============          compose_b (209..496)  — mutually independent ============
__global__ __launch_bounds__(256) void stage1_kernel(
    const bf16* edge_attr, const bf16* W_we, const bf16* b_we, const bf16* x,
    const bf16* Wrel1, const bf16* brel1, const bf16* Wroot1,
    const bf16* Wrel2, const bf16* brel2, const bf16* Wroot2,
    const bf16* W_o, const bf16* b_o, const bf16* W_out, const bf16* b_out,
    const bf16* W_in, const bf16* b_in, const bf16* b_qkv, const bf16* W_qkv,
    float* x2out, float* wo_eff, float* bq_eff, float* bk_eff, float* bv_eff, float* sc,
    float* WqT, float* WkT, bf16* W2b) {
    int blk = blockIdx.x, tid = threadIdx.x;
    if (blk < 16) {  // ---- graphconv, one block per batch ----
        int b = blk;
        __shared__ float s_ws[N_ * N_];
        __shared__ float s_x[N_ * 5], s_agg1[N_ * 5];
        __shared__ float s_x1[N_ * 32], s_agg2[N_ * 32];
        float we0 = bf(W_we, 0), we1 = bf(W_we, 1), we2 = bf(W_we, 2), bw = bf(b_we, 0);
        for (int idx = tid; idx < N_ * N_; idx += 256) {
            int i = idx / N_, j = idx % N_;
            float v = 0.f;
            if (i != j) {
                int p = i * 47 + (j < i ? j : j - 1);
                int e = (b * PAIRS + p) * 2;
                float w0 = fmaxf(we0 * bf(edge_attr, (e + 0) * 2) + we1 + bw, 0.f);
                float w1 = fmaxf(we0 * bf(edge_attr, (e + 1) * 2) + we2 + bw, 0.f);
                v = w0 + w1;
            }
            s_ws[idx] = v;
        }
        for (int idx = tid; idx < N_ * 5; idx += 256) s_x[idx] = bf(x, b * N_ * 5 + idx);
        __syncthreads();
        if (tid < 240) {
            int j = tid / 5, f = tid % 5;
            float a = 0.f;
            for (int i = 0; i < N_; i++) a += s_ws[i * N_ + j] * s_x[i * 5 + f];
            s_agg1[tid] = a;
        }
        __syncthreads();
        for (int o = tid; o < N_ * 32; o += 256) {
            int j = o >> 5, h = o & 31;
            float a = bf(brel1, h);
            for (int f = 0; f < 5; f++)
                a += bf(Wrel1, h * 5 + f) * s_agg1[j * 5 + f] +
                     bf(Wroot1, h * 5 + f) * s_x[j * 5 + f];
            s_x1[o] = fmaxf(a, 0.f);
        }
        __syncthreads();
        for (int o = tid; o < N_ * 32; o += 256) {
            int j = o >> 5, h = o & 31;
            float a = 0.f;
            for (int i = 0; i < N_; i++) a += s_ws[i * N_ + j] * s_x1[i * 32 + h];
            s_agg2[o] = a;
        }
        __syncthreads();
        for (int o = tid; o < N_ * 64; o += 256) {
            int j = o >> 6, h2 = o & 63;
            float a = bf(brel2, h2);
            for (int h1 = 0; h1 < 32; h1++)
                a += bf(Wrel2, h2 * 32 + h1) * s_agg2[j * 32 + h1] +
                     bf(Wroot2, h2 * 32 + h1) * s_x1[j * 32 + h1];
            x2out[(b * N_ + j) * 64 + h2] = fmaxf(a, 0.f);
        }
    } else if (blk < 209) {  // ---- compose_a1 ----
        int a = blk - 16;  // 0..191 outputs; 192 = co
        int wave = tid >> 6, lane = tid & 63;
        float partial = 0.f;
        if (a < 192) {
            if (wave == 0) {
                for (int m = lane; m < 192; m += 64)
                    partial += bf(W_o, m) * bf(W_out, m * 192 + a);
            } else {
                int row = (wave - 1) * 192 + a;
                for (int m = lane; m < 192; m += 64)
                    partial += bf(W_in, row * 192 + m) * bf(b_qkv, (wave - 1) * 192 + m);
            }
        } else if (wave == 0) {
            for (int m = lane; m < 192; m += 64) partial += bf(W_o, m) * bf(b_out, m);
        }
        for (int off = 32; off; off >>= 1) partial += __shfl_xor(partial, off, 64);
        if (lane == 0) {
            if (a < 192) {
                if (wave == 0) wo_eff[a] = partial;
                else if (wave == 1) bq_eff[a] = partial + bf(b_in, a);
                else if (wave == 2) bk_eff[a] = partial + bf(b_in, 192 + a);
                else bv_eff[a] = partial + bf(b_in, 384 + a);
            } else if (wave == 0) sc[1] = partial + bf(b_o, 0);
        }
    } else {  // ---- compose_b: Wq/Wk transposed tables + W2b bf16 ----
        int idx = (blk - 209) * 256 + tid;  // 0 .. 2*D*D-1
        if (idx < D_ * D_) {
            int a = idx / D_, c = idx % D_;
            float acc = 0.f;
            for (int m = 0; m < D_; m++) acc += bf(W_in, a * D_ + m) * bf(W_qkv, m * D_ + c);
            WqT[c * D_ + a] = acc;
            if (c >= 64 && c < 128) W2b[a * 64 + (c - 64)] = __float2bfloat16(acc);
        } else {
            int t = idx - D_ * D_, a = t / D_, c = t % D_;
            float acc = 0.f;
            for (int m = 0; m < D_; m++)
                acc += bf(W_in, (D_ + a) * D_ + m) * bf(W_qkv, (D_ + m) * D_ + c);
            WkT[c * D_ + a] = acc;
            if (c >= 64 && c < 128) W2b[(192 + a) * 64 + (c - 64)] = __float2bfloat16(acc);
        }
    }
}

// ============ STAGE 2: sc0 (block 0) | wvl quadratic (1..192) | nodeproj (193..960) ====
__global__ __launch_bounds__(256) void stage2_kernel(
    const bf16* W_in, const bf16* W_qkv, const float* wo_eff, const float* bv_eff,
    const float* x2, const float* WqT, const float* WkT,
    const float* bq_eff, const float* bk_eff,
    float* wvl, float* sc, float* Tq1, float* Tq3, float* Tk1, float* Tk3) {
    int blk = blockIdx.x, tid = threadIdx.x;
    if (blk == 0) {
        if (tid < 64) {
            float partial = 0.f;
            for (int aa = tid; aa < 192; aa += 64) partial += wo_eff[aa] * bv_eff[aa];
            for (int off = 32; off; off >>= 1) partial += __shfl_xor(partial, off, 64);
            if (tid == 0) sc[0] = partial;
        }
    } else if (blk < 193) {
        int w = blk - 1;
        __shared__ float s_tm[192];
        if (tid < 192) {
            float tm = 0.f;
            for (int aa = 0; aa < 192; aa++)
                tm += wo_eff[aa] * bf(W_in, (384 + aa) * 192 + tid);
            s_tm[tid] = tm;
        }
        __syncthreads();
        if (tid < 64) {
            float partial = 0.f;
            for (int m = tid; m < 192; m += 64)
                partial += s_tm[m] * bf(W_qkv, (384 + m) * 192 + w);
            for (int off = 32; off; off >>= 1) partial += __shfl_xor(partial, off, 64);
            if (tid == 0) wvl[w] = partial;
        }
    } else {
        int n = blk - 193;
        __shared__ float sx[64];
        if (tid < 64) sx[tid] = x2[n * 64 + tid];
        __syncthreads();
        if (tid < D_) {
            int a = tid;
            float q1 = bq_eff[a], q3 = 0.f, k1 = bk_eff[a], k3 = 0.f;
            for (int c = 0; c < 64; c++) {
                float xv = sx[c];
                q1 += WqT[c * D_ + a] * xv;
                q3 += WqT[(128 + c) * D_ + a] * xv;
                k1 += WkT[c * D_ + a] * xv;
                k3 += WkT[(128 + c) * D_ + a] * xv;
            }
            Tq1[n * D_ + a] = q1; Tq3[n * D_ + a] = q3;
            Tk1[n * D_ + a] = k1; Tk3[n * D_ + a] = k3;
        }
    }
}

// ============ K3: MFMA per-edge mid-GEMM — writes K in MFMA-B-permuted layout ========
__global__ __launch_bounds__(256) void qkvmid_kernel(
    const bf16* edge_attr, const bf16* W_ee, const bf16* b_ee, const bf16* W2b,
    const float* wvl, const float* sc, const float* x2,
    const float* Tq1, const float* Tq3, const float* Tk1, const float* Tk3,
    bf16* Q, bf16* Kp, float* vl) {
    __shared__ short s_wk[32 * 72];
    __shared__ float s_wvl[192];
    __shared__ int s_ni[32], s_nj[32], s_koff[32];
    __shared__ float s_wraw[32], s_cls[32];
    int tid = threadIdx.x, base = blockIdx.x * 32;
    int wave = tid >> 6, lane = tid & 63;
    int l5 = lane & 31, h5 = lane >> 5;

    short8 bfr[3][4];
    #pragma unroll
    for (int tt = 0; tt < 3; tt++) {
        int ta = wave + tt * 4;
        const short* wrow = (const short*)W2b + (ta * 32 + l5) * 64;
        #pragma unroll
        for (int kc = 0; kc < 4; kc++)
            bfr[tt][kc] = *(const short8*)(wrow + kc * 16 + h5 * 8);
    }

    if (tid < 192) s_wvl[tid] = wvl[tid];
    if (tid < 32) {
        int kk_g = base + tid;
        int b = kk_g / S_, kk = kk_g % S_;
        int q = kk >> 1, cls = kk & 1;
        int i = (int)((1.0f + sqrtf(8.0f * (float)q + 1.0f)) * 0.5f);
        while (i * (i - 1) / 2 > q) --i;
        while ((i + 1) * i / 2 <= q) ++i;
        int j = q - i * (i - 1) / 2;
        s_ni[tid] = b * N_ + i; s_nj[tid] = b * N_ + j;
        int e = (b * PAIRS + i * 47 + j) * 2 + cls;
        s_wraw[tid] = bf(edge_attr, e * 2);
        s_cls[tid] = (float)cls;
        s_koff[tid] = (b * KITERS + (kk >> 5)) * KPB + (kk & 31) * 8;
    }
    __syncthreads();
    for (int idx = tid; idx < 32 * 64; idx += 256) {
        int t = idx >> 6, h = idx & 63;
        int cls = (int)s_cls[t];
        float v = bf(W_ee, h * 3) * s_wraw[t] + bf(W_ee, h * 3 + 1 + cls) + bf(b_ee, h);
        bf16 bv = __float2bfloat16(fmaxf(v, 0.f));
        s_wk[t * 72 + h] = *reinterpret_cast<short*>(&bv);
    }
    __syncthreads();

    short8 af[4];
    #pragma unroll
    for (int kc = 0; kc < 4; kc++)
        af[kc] = *(const short8*)&s_wk[l5 * 72 + kc * 16 + h5 * 8];

    int tl[16], niv[16], njv[16];
    #pragma unroll
    for (int r = 0; r < 16; r++) {
        int t = (r & 3) + 8 * (r >> 2) + 4 * h5;
        tl[r] = t; niv[r] = s_ni[t]; njv[r] = s_nj[t];
    }

    #pragma unroll
    for (int tt = 0; tt < 3; tt++) {
        int ta = wave + tt * 4;
        bool isq = ta < 6;
        int ag = (isq ? ta : ta - 6) * 32 + l5;
        float16v c;
        #pragma unroll
        for (int r = 0; r < 16; r++) c[r] = 0.f;
        #pragma unroll
        for (int kc = 0; kc < 4; kc++)
            c = __builtin_amdgcn_mfma_f32_32x32x16_bf16(af[kc], bfr[tt][kc], c, 0, 0, 0);
        const float* T1 = isq ? Tq1 : Tk1;
        const float* T3 = isq ? Tq3 : Tk3;
        if (isq) {
            #pragma unroll
            for (int r = 0; r < 16; r++) {
                float v = (c[r] + T1[niv[r] * D_ + ag] + T3[njv[r] * D_ + ag]) * QSCALE;
                Q[(long)(base + tl[r]) * D_ + ag] = __float2bfloat16(v);
            }
        } else {
            int kc = ag >> 4, h5w = (ag >> 3) & 1, e = ag & 7;
            int coff = kc * 512 + h5w * 256 + e;
            #pragma unroll
            for (int r = 0; r < 16; r++) {
                float v = c[r] + T1[niv[r] * D_ + ag] + T3[njv[r] * D_ + ag];
                Kp[s_koff[tl[r]] + coff] = __float2bfloat16(v);
            }
        }
    }
    {
        int t = tid >> 3, g = tid & 7;
        const float* xi = &x2[s_ni[t] * 64];
        const float* xj = &x2[s_nj[t] * 64];
        float v = 0.f;
        #pragma unroll
        for (int hh = 0; hh < 8; hh++) {
            int h = g * 8 + hh;
            v += s_wvl[h] * xi[h] + s_wvl[128 + h] * xj[h] +
                 s_wvl[64 + h] * u2f((unsigned short)s_wk[t * 72 + h]);
        }
        v += __shfl_xor(v, 1, 64);
        v += __shfl_xor(v, 2, 64);
        v += __shfl_xor(v, 4, 64);
        if (g == 0) vl[base + t] = v + sc[0];
    }
}

// ============ K4: attn — permuted-K, barrier-free, 2 q-tiles/wave, ONE launch ========
__global__ __launch_bounds__(256) void attn_kernel(const bf16* Q, const bf16* Kp,
                                                   const float* vl, float* part) {
    // 1152 blocks = 8 XCDs x (2 batches x 8 chunks x 9 q-groups); 4 waves x 2 q-tiles
    int x = blockIdx.x;
    int rr = x & 7, rest = x >> 3;       // rest 0..143
    int hi = rest >= 72;
    int b = rr + 8 * hi;
    int s = rest - 72 * hi;              // 0..71
    int chunk = s / 9, qg = s % 9;
    int tid = threadIdx.x;
    int wave = tid >> 6, lane = tid & 63;
    int n5 = lane & 31, h5 = lane >> 5;
    int qtA = qg * 8 + wave * 2;         // 0..70 even — always valid
    int qtB = qtA + 1;                   // 1..71 (71 invalid)
    bool validB = qtB < QTILES;
    int t0 = chunk * 9;
    int nit = (chunk == 7) ? 8 : 9;

    short8 qfA[12], qfB[12];
    {
        int qrowA = b * S_ + qtA * 32 + n5;
        int qrowB = b * S_ + qtB * 32 + n5;
        if (qrowB > B_ * S_ - 1) qrowB = B_ * S_ - 1;
        const short* qpA = (const short*)Q + (long)qrowA * D_;
        const short* qpB = (const short*)Q + (long)qrowB * D_;
        #pragma unroll
        for (int kc = 0; kc < 12; kc++) {
            qfA[kc] = *(const short8*)(qpA + kc * 16 + h5 * 8);
            qfB[kc] = *(const short8*)(qpB + kc * 16 + h5 * 8);
        }
    }

    float lrA[16], arA[16], lrB[16], arB[16];
    #pragma unroll
    for (int r = 0; r < 16; r++) { lrA[r] = 0.f; arA[r] = 0.f; lrB[r] = 0.f; arB[r] = 0.f; }

    const short* Kb = (const short*)Kp + (long)b * KITERS * KPB + h5 * 256 + n5 * 8;
    const float* vlb = vl + b * S_;

    for (int k = 0; k < nit; ++k) {
        int it = t0 + k;
        const short* kp = Kb + it * KPB;
        int row = it * 32 + n5;
        float vlv = vlb[row < S_ ? row : S_ - 1];
        float16v cA, cB;
        #pragma unroll
        for (int r = 0; r < 16; r++) { cA[r] = 0.f; cB[r] = 0.f; }
        #pragma unroll
        for (int kc = 0; kc < 12; kc++) {           // rolling B-frag: load once, 2 MFMAs
            short8 bfr = *(const short8*)(kp + kc * 512);
            cA = __builtin_amdgcn_mfma_f32_32x32x16_bf16(qfA[kc], bfr, cA, 0, 0, 0);
            cB = __builtin_amdgcn_mfma_f32_32x32x16_bf16(qfB[kc], bfr, cB, 0, 0, 0);
        }
        if (it != KITERS - 1) {
            #pragma unroll
            for (int r = 0; r < 16; r++) {
                float pA = __builtin_amdgcn_exp2f(cA[r]);
                float pB = __builtin_amdgcn_exp2f(cB[r]);
                lrA[r] += pA; arA[r] += pA * vlv;
                lrB[r] += pB; arB[r] += pB * vlv;
            }
        } else {
            bool kv = n5 < 16;
            #pragma unroll
            for (int r = 0; r < 16; r++) {
                float pA = kv ? __builtin_amdgcn_exp2f(cA[r]) : 0.f;
                float pB = kv ? __builtin_amdgcn_exp2f(cB[r]) : 0.f;
                lrA[r] += pA; arA[r] += pA * vlv;
                lrB[r] += pB; arB[r] += pB * vlv;
            }
        }
    }

    #pragma unroll
    for (int r = 0; r < 16; r++) {
        float l = lrA[r], a = arA[r];
        #pragma unroll
        for (int off = 1; off < 32; off <<= 1) {
            l += __shfl_xor(l, off, 64);
            a += __shfl_xor(a, off, 64);
        }
        if (n5 == 0) {
            int qrow = qtA * 32 + (r & 3) + 8 * (r >> 2) + 4 * h5;
            float2v pv2 = {l, a};
            *(float2v*)&part[((long)(b * S_ + qrow) * 8 + chunk) * 2] = pv2;
        }
    }
    if (validB) {
        #pragma unroll
        for (int r = 0; r < 16; r++) {
            float l = lrB[r], a = arB[r];
            #pragma unroll
            for (int off = 1; off < 32; off <<= 1) {
                l += __shfl_xor(l, off, 64);
                a += __shfl_xor(a, off, 64);
            }
            if (n5 == 0) {
                int qrow = qtB * 32 + (r & 3) + 8 * (r >> 2) + 4 * h5;
                if (qrow < S_) {
                    float2v pv2 = {l, a};
                    *(float2v*)&part[((long)(b * S_ + qrow) * 8 + chunk) * 2] = pv2;
                }
            }
        }
    }
}

// ============ K5: merge partials + pairing/argmin ============
__global__ __launch_bounds__(256) void final_kernel(const float* part, const float* sc,
                                                    float* out) {
    int idx = blockIdx.x * 256 + threadIdx.x;
    if (idx >= B_ * SH) return;
    int b = idx / SH, p = idx % SH;
    int i = (int)((1.0f + sqrtf(8.0f * (float)p + 1.0f)) * 0.5f);
    while (i * (i - 1) / 2 > p) --i;
    while ((i + 1) * i / 2 <= p) ++i;
    int j = p - i * (i - 1) / 2;
    float co = sc[1];
    float lg[2];
    #pragma unroll
    for (int t = 0; t < 2; t++) {
        long g = (long)b * S_ + 2 * p + t;
        float l = 0.f, a = 0.f;
        #pragma unroll
        for (int c = 0; c < 8; c++) {
            float2v pc = *(const float2v*)&part[(g * 8 + c) * 2];
            l += pc.x;
            a += pc.y;
        }
        lg[t] = sanitize(a / l + co);
    }
    int ind = (lg[1] < lg[0]) ? 1 : 0;
    float ef = ind ? lg[1] : lg[0];
    out[(b * SH + p) * 2 + 0] = (float)(b * N_ + i);
    out[(b * SH + p) * 2 + 1] = (float)(b * N_ + j);
    out[2 * B_ * SH + idx] = ef;
    out[2 * B_ * SH + B_ * SH + idx] = (float)ind;
}

extern "C" void kernel_launch(void* const* d_in, const int* in_sizes, int n_in,
                              void* d_out, int out_size, void* d_ws, size_t ws_size,
                              hipStream_t stream) {
    const bf16* x         = (const bf16*)d_in[0];
    const bf16* edge_attr = (const bf16*)d_in[2];
    const bf16* W_we   = (const bf16*)d_in[5];
    const bf16* b_we   = (const bf16*)d_in[6];
    const bf16* Wrel1  = (const bf16*)d_in[7];
    const bf16* brel1  = (const bf16*)d_in[8];
    const bf16* Wroot1 = (const bf16*)d_in[9];
    const bf16* Wrel2  = (const bf16*)d_in[10];
    const bf16* brel2  = (const bf16*)d_in[11];
    const bf16* Wroot2 = (const bf16*)d_in[12];
    const bf16* W_ee   = (const bf16*)d_in[13];
    const bf16* b_ee   = (const bf16*)d_in[14];
    const bf16* W_qkv  = (const bf16*)d_in[15];
    const bf16* b_qkv  = (const bf16*)d_in[16];
    const bf16* W_in   = (const bf16*)d_in[17];
    const bf16* b_in   = (const bf16*)d_in[18];
    const bf16* W_out  = (const bf16*)d_in[19];
    const bf16* b_out  = (const bf16*)d_in[20];
    const bf16* W_o    = (const bf16*)d_in[21];
    const bf16* b_o    = (const bf16*)d_in[22];

    float* w = (float*)d_ws;
    float* WqT    = w;                  // 36864
    float* WkT    = WqT + 36864;        // 36864
    float* bq_eff = WkT + 36864;        // 192
    float* bk_eff = bq_eff + 192;
    float* bv_eff = bk_eff + 192;
    float* wo_eff = bv_eff + 192;
    float* wvl    = wo_eff + 192;       // 192
    float* sc     = wvl + 192;          // 64 (2 used)
    float* x2     = sc + 64;            // 49152
    float* vl     = x2 + 49152;         // 36096
    float* part   = vl + 36096;         // 577536
    bf16*  Q      = (bf16*)(part + 577536);     // EK*192 bf16
    bf16*  Kp     = Q + (long)EK * D_;          // 16*71*6144 bf16 (permuted)
    bf16*  W2b    = Kp + (long)B_ * KITERS * KPB;  // 384*64 bf16
    float* Tq1    = (float*)(W2b + 384 * 64);
    float* Tq3    = Tq1 + NODES * D_;
    float* Tk1    = Tq3 + NODES * D_;
    float* Tk3    = Tk1 + NODES * D_;
    // total ~36 MB of 256 MB workspace

    stage1_kernel<<<497, 256, 0, stream>>>(edge_attr, W_we, b_we, x, Wrel1, brel1, Wroot1,
                                           Wrel2, brel2, Wroot2, W_o, b_o, W_out, b_out,
                                           W_in, b_in, b_qkv, W_qkv,
                                           x2, wo_eff, bq_eff, bk_eff, bv_eff, sc,
                                           WqT, WkT, W2b);
    stage2_kernel<<<961, 256, 0, stream>>>(W_in, W_qkv, wo_eff, bv_eff, x2, WqT, WkT,
                                           bq_eff, bk_eff, wvl, sc, Tq1, Tq3, Tk1, Tk3);
    qkvmid_kernel<<<EK / 32, 256, 0, stream>>>(edge_attr, W_ee, b_ee, W2b, wvl, sc, x2,
                                               Tq1, Tq3, Tk1, Tk3, Q, Kp, vl);
    attn_kernel<<<1152, 256, 0, stream>>>(Q, Kp, vl, part);
    final_kernel<<<(B_ * SH + 255) / 256, 256, 0, stream>>>(part, sc, (float*)d_out);
}

// Round 19
// 238.108 us; speedup vs baseline: 1.3138x; 1.2308x over previous
//
#include <hip/hip_runtime.h>
#include <hip/hip_bf16.h>

typedef __hip_bfloat16 bf16;
typedef __attribute__((ext_vector_type(8))) short short8;
typedef __attribute__((ext_vector_type(16))) float float16v;
typedef __attribute__((ext_vector_type(2))) float float2v;

#define B_     16
#define N_     48
#define NODES  768
#define PAIRS  2256
#define EK     36096
#define S_     2256
#define SH     1128
#define D_     192
#define KITERS 71
#define QTILES 71
#define QSCALE 0.10411754f  // log2(e)/sqrt(192): folded into Q at store

__device__ __forceinline__ float bf(const bf16* p, int i) { return __bfloat162float(p[i]); }
__device__ __forceinline__ float u2f(unsigned short u) {
    return __uint_as_float(((unsigned int)u) << 16);
}
__device__ __forceinline__ float sanitize(float v) {
    if (v > -1e4f && v < 1e4f) return v;
    if (v >= 1e4f) return 1e4f;
    if (v <= -1e4f) return -1e4f;
    return 0.f;  // NaN
}

// ============ STAGE 1: graphconv (blocks 0..15) | compose_a1 (16..208) |
// ============          compose_b (209..496)  — mutually independent ============
__global__ __launch_bounds__(256) void stage1_kernel(
    const bf16* edge_attr, const bf16* W_we, const bf16* b_we, const bf16* x,
    const bf16* Wrel1, const bf16* brel1, const bf16* Wroot1,
    const bf16* Wrel2, const bf16* brel2, const bf16* Wroot2,
    const bf16* W_o, const bf16* b_o, const bf16* W_out, const bf16* b_out,
    const bf16* W_in, const bf16* b_in, const bf16* b_qkv, const bf16* W_qkv,
    float* x2out, float* wo_eff, float* bq_eff, float* bk_eff, float* bv_eff, float* sc,
    float* WqT, float* WkT, bf16* W2b) {
    int blk = blockIdx.x, tid = threadIdx.x;
    if (blk < 16) {  // ---- graphconv, one block per batch ----
        int b = blk;
        __shared__ float s_ws[N_ * N_];
        __shared__ float s_x[N_ * 5], s_agg1[N_ * 5];
        __shared__ float s_x1[N_ * 32], s_agg2[N_ * 32];
        float we0 = bf(W_we, 0), we1 = bf(W_we, 1), we2 = bf(W_we, 2), bw = bf(b_we, 0);
        for (int idx = tid; idx < N_ * N_; idx += 256) {
            int i = idx / N_, j = idx % N_;
            float v = 0.f;
            if (i != j) {
                int p = i * 47 + (j < i ? j : j - 1);
                int e = (b * PAIRS + p) * 2;
                float w0 = fmaxf(we0 * bf(edge_attr, (e + 0) * 2) + we1 + bw, 0.f);
                float w1 = fmaxf(we0 * bf(edge_attr, (e + 1) * 2) + we2 + bw, 0.f);
                v = w0 + w1;
            }
            s_ws[idx] = v;
        }
        for (int idx = tid; idx < N_ * 5; idx += 256) s_x[idx] = bf(x, b * N_ * 5 + idx);
        __syncthreads();
        if (tid < 240) {
            int j = tid / 5, f = tid % 5;
            float a = 0.f;
            for (int i = 0; i < N_; i++) a += s_ws[i * N_ + j] * s_x[i * 5 + f];
            s_agg1[tid] = a;
        }
        __syncthreads();
        for (int o = tid; o < N_ * 32; o += 256) {
            int j = o >> 5, h = o & 31;
            float a = bf(brel1, h);
            for (int f = 0; f < 5; f++)
                a += bf(Wrel1, h * 5 + f) * s_agg1[j * 5 + f] +
                     bf(Wroot1, h * 5 + f) * s_x[j * 5 + f];
            s_x1[o] = fmaxf(a, 0.f);
        }
        __syncthreads();
        for (int o = tid; o < N_ * 32; o += 256) {
            int j = o >> 5, h = o & 31;
            float a = 0.f;
            for (int i = 0; i < N_; i++) a += s_ws[i * N_ + j] * s_x1[i * 32 + h];
            s_agg2[o] = a;
        }
        __syncthreads();
        for (int o = tid; o < N_ * 64; o += 256) {
            int j = o >> 6, h2 = o & 63;
            float a = bf(brel2, h2);
            for (int h1 = 0; h1 < 32; h1++)
                a += bf(Wrel2, h2 * 32 + h1) * s_agg2[j * 32 + h1] +
                     bf(Wroot2, h2 * 32 + h1) * s_x1[j * 32 + h1];
            x2out[(b * N_ + j) * 64 + h2] = fmaxf(a, 0.f);
        }
    } else if (blk < 209) {  // ---- compose_a1 ----
        int a = blk - 16;  // 0..191 outputs; 192 = co
        int wave = tid >> 6, lane = tid & 63;
        float partial = 0.f;
        if (a < 192) {
            if (wave == 0) {
                for (int m = lane; m < 192; m += 64)
                    partial += bf(W_o, m) * bf(W_out, m * 192 + a);
            } else {
                int row = (wave - 1) * 192 + a;
                for (int m = lane; m < 192; m += 64)
                    partial += bf(W_in, row * 192 + m) * bf(b_qkv, (wave - 1) * 192 + m);
            }
        } else if (wave == 0) {
            for (int m = lane; m < 192; m += 64) partial += bf(W_o, m) * bf(b_out, m);
        }
        for (int off = 32; off; off >>= 1) partial += __shfl_xor(partial, off, 64);
        if (lane == 0) {
            if (a < 192) {
                if (wave == 0) wo_eff[a] = partial;
                else if (wave == 1) bq_eff[a] = partial + bf(b_in, a);
                else if (wave == 2) bk_eff[a] = partial + bf(b_in, 192 + a);
                else bv_eff[a] = partial + bf(b_in, 384 + a);
            } else if (wave == 0) sc[1] = partial + bf(b_o, 0);
        }
    } else {  // ---- compose_b: Wq/Wk transposed tables + W2b bf16 ----
        int idx = (blk - 209) * 256 + tid;  // 0 .. 2*D*D-1
        if (idx < D_ * D_) {
            int a = idx / D_, c = idx % D_;
            float acc = 0.f;
            for (int m = 0; m < D_; m++) acc += bf(W_in, a * D_ + m) * bf(W_qkv, m * D_ + c);
            WqT[c * D_ + a] = acc;
            if (c >= 64 && c < 128) W2b[a * 64 + (c - 64)] = __float2bfloat16(acc);
        } else {
            int t = idx - D_ * D_, a = t / D_, c = t % D_;
            float acc = 0.f;
            for (int m = 0; m < D_; m++)
                acc += bf(W_in, (D_ + a) * D_ + m) * bf(W_qkv, (D_ + m) * D_ + c);
            WkT[c * D_ + a] = acc;
            if (c >= 64 && c < 128) W2b[(192 + a) * 64 + (c - 64)] = __float2bfloat16(acc);
        }
    }
}

// ============ STAGE 2: sc0 (block 0) | wvl quadratic (1..192) | nodeproj (193..960) ====
__global__ __launch_bounds__(256) void stage2_kernel(
    const bf16* W_in, const bf16* W_qkv, const float* wo_eff, const float* bv_eff,
    const float* x2, const float* WqT, const float* WkT,
    const float* bq_eff, const float* bk_eff,
    float* wvl, float* sc, float* Tq1, float* Tq3, float* Tk1, float* Tk3) {
    int blk = blockIdx.x, tid = threadIdx.x;
    if (blk == 0) {
        if (tid < 64) {
            float partial = 0.f;
            for (int aa = tid; aa < 192; aa += 64) partial += wo_eff[aa] * bv_eff[aa];
            for (int off = 32; off; off >>= 1) partial += __shfl_xor(partial, off, 64);
            if (tid == 0) sc[0] = partial;
        }
    } else if (blk < 193) {
        int w = blk - 1;
        __shared__ float s_tm[192];
        if (tid < 192) {
            float tm = 0.f;
            for (int aa = 0; aa < 192; aa++)
                tm += wo_eff[aa] * bf(W_in, (384 + aa) * 192 + tid);
            s_tm[tid] = tm;
        }
        __syncthreads();
        if (tid < 64) {
            float partial = 0.f;
            for (int m = tid; m < 192; m += 64)
                partial += s_tm[m] * bf(W_qkv, (384 + m) * 192 + w);
            for (int off = 32; off; off >>= 1) partial += __shfl_xor(partial, off, 64);
            if (tid == 0) wvl[w] = partial;
        }
    } else {
        int n = blk - 193;
        __shared__ float sx[64];
        if (tid < 64) sx[tid] = x2[n * 64 + tid];
        __syncthreads();
        if (tid < D_) {
            int a = tid;
            float q1 = bq_eff[a], q3 = 0.f, k1 = bk_eff[a], k3 = 0.f;
            for (int c = 0; c < 64; c++) {
                float xv = sx[c];
                q1 += WqT[c * D_ + a] * xv;
                q3 += WqT[(128 + c) * D_ + a] * xv;
                k1 += WkT[c * D_ + a] * xv;
                k3 += WkT[(128 + c) * D_ + a] * xv;
            }
            Tq1[n * D_ + a] = q1; Tq3[n * D_ + a] = q3;
            Tk1[n * D_ + a] = k1; Tk3[n * D_ + a] = k3;
        }
    }
}

// ============ K3: MFMA per-edge mid-GEMM — W2 B-frags in REGISTERS (R14) ============
__global__ __launch_bounds__(256) void qkvmid_kernel(
    const bf16* edge_attr, const bf16* W_ee, const bf16* b_ee, const bf16* W2b,
    const float* wvl, const float* sc, const float* x2,
    const float* Tq1, const float* Tq3, const float* Tk1, const float* Tk3,
    bf16* Q, bf16* K, float* vl) {
    __shared__ short s_wk[32 * 72];
    __shared__ float s_wvl[192];
    __shared__ int s_ni[32], s_nj[32];
    __shared__ float s_wraw[32], s_cls[32];
    int tid = threadIdx.x, base = blockIdx.x * 32;
    int wave = tid >> 6, lane = tid & 63;
    int l5 = lane & 31, h5 = lane >> 5;

    short8 bfr[3][4];
    #pragma unroll
    for (int tt = 0; tt < 3; tt++) {
        int ta = wave + tt * 4;
        const short* wrow = (const short*)W2b + (ta * 32 + l5) * 64;
        #pragma unroll
        for (int kc = 0; kc < 4; kc++)
            bfr[tt][kc] = *(const short8*)(wrow + kc * 16 + h5 * 8);
    }

    if (tid < 192) s_wvl[tid] = wvl[tid];
    if (tid < 32) {
        int kk_g = base + tid;
        int b = kk_g / S_, kk = kk_g % S_;
        int q = kk >> 1, cls = kk & 1;
        int i = (int)((1.0f + sqrtf(8.0f * (float)q + 1.0f)) * 0.5f);
        while (i * (i - 1) / 2 > q) --i;
        while ((i + 1) * i / 2 <= q) ++i;
        int j = q - i * (i - 1) / 2;
        s_ni[tid] = b * N_ + i; s_nj[tid] = b * N_ + j;
        int e = (b * PAIRS + i * 47 + j) * 2 + cls;
        s_wraw[tid] = bf(edge_attr, e * 2);
        s_cls[tid] = (float)cls;
    }
    __syncthreads();
    for (int idx = tid; idx < 32 * 64; idx += 256) {
        int t = idx >> 6, h = idx & 63;
        int cls = (int)s_cls[t];
        float v = bf(W_ee, h * 3) * s_wraw[t] + bf(W_ee, h * 3 + 1 + cls) + bf(b_ee, h);
        bf16 bv = __float2bfloat16(fmaxf(v, 0.f));
        s_wk[t * 72 + h] = *reinterpret_cast<short*>(&bv);
    }
    __syncthreads();

    short8 af[4];
    #pragma unroll
    for (int kc = 0; kc < 4; kc++)
        af[kc] = *(const short8*)&s_wk[l5 * 72 + kc * 16 + h5 * 8];

    int tl[16], niv[16], njv[16];
    #pragma unroll
    for (int r = 0; r < 16; r++) {
        int t = (r & 3) + 8 * (r >> 2) + 4 * h5;
        tl[r] = t; niv[r] = s_ni[t]; njv[r] = s_nj[t];
    }

    #pragma unroll
    for (int tt = 0; tt < 3; tt++) {
        int ta = wave + tt * 4;
        bool isq = ta < 6;
        int ag = (isq ? ta : ta - 6) * 32 + l5;
        float16v c;
        #pragma unroll
        for (int r = 0; r < 16; r++) c[r] = 0.f;
        #pragma unroll
        for (int kc = 0; kc < 4; kc++)
            c = __builtin_amdgcn_mfma_f32_32x32x16_bf16(af[kc], bfr[tt][kc], c, 0, 0, 0);
        const float* T1 = isq ? Tq1 : Tk1;
        const float* T3 = isq ? Tq3 : Tk3;
        bf16* Out = isq ? Q : K;
        #pragma unroll
        for (int r = 0; r < 16; r++) {
            float v = c[r] + T1[niv[r] * D_ + ag] + T3[njv[r] * D_ + ag];
            if (isq) v *= QSCALE;
            Out[(long)(base + tl[r]) * D_ + ag] = __float2bfloat16(v);
        }
    }
    {
        int t = tid >> 3, g = tid & 7;
        const float* xi = &x2[s_ni[t] * 64];
        const float* xj = &x2[s_nj[t] * 64];
        float v = 0.f;
        #pragma unroll
        for (int hh = 0; hh < 8; hh++) {
            int h = g * 8 + hh;
            v += s_wvl[h] * xi[h] + s_wvl[128 + h] * xj[h] +
                 s_wvl[64 + h] * u2f((unsigned short)s_wk[t * 72 + h]);
        }
        v += __shfl_xor(v, 1, 64);
        v += __shfl_xor(v, 2, 64);
        v += __shfl_xor(v, 4, 64);
        if (g == 0) vl[base + t] = v + sc[0];
    }
}

// ============ K4: attn — R12/R14 version (512 thr, LDS dbuf, reg prefetch) ============
__global__ __launch_bounds__(512) void attn_kernel(const bf16* Q, const bf16* K,
                                                   const float* vl, float* part) {
    // 1152 blocks = 8 XCDs x (2 batches x 8 chunks x 9 q-groups)
    int x = blockIdx.x;
    int rr = x & 7, rest = x >> 3;       // rest 0..143
    int hi = rest >= 72;
    int b = rr + 8 * hi;
    int s = rest - 72 * hi;              // 0..71
    int chunk = s / 9, qg = s % 9;
    int tid = threadIdx.x;
    int wave = tid >> 6, lane = tid & 63;
    int n5 = lane & 31, h5 = lane >> 5;
    int qt = qg * 8 + wave;              // 0..71 (71 invalid)
    bool qvalid = qt < QTILES;
    int t0 = chunk * 9;
    int nit = (chunk == 7) ? 8 : 9;

    __shared__ short s_k[2][32 * 200];
    __shared__ float s_vl[2][32];

    int row0 = tid / 24, cc0 = tid % 24;
    int c1 = tid + 512;
    int row1 = c1 / 24, cc1 = c1 % 24;
    bool has1 = tid < 256;

    short8 qf[12];
    {
        int qrow = b * S_ + qt * 32 + n5;
        if (qrow > B_ * S_ - 1) qrow = B_ * S_ - 1;
        const short* qp = (const short*)Q + (long)qrow * D_;
        #pragma unroll
        for (int kc = 0; kc < 12; kc++) qf[kc] = *(const short8*)(qp + kc * 16 + h5 * 8);
    }

    float lr[16], ar[16];
    #pragma unroll
    for (int r = 0; r < 16; r++) { lr[r] = 0.f; ar[r] = 0.f; }

    uint4 p0, p1; float pv = 0.f;
    {
        int key = t0 * 32 + row0;
        int gk = b * S_ + (key < S_ ? key : S_ - 1);
        p0 = *(const uint4*)((const short*)K + (long)gk * D_ + cc0 * 8);
        if (has1) {
            int key1 = t0 * 32 + row1;
            int gk1 = b * S_ + (key1 < S_ ? key1 : S_ - 1);
            p1 = *(const uint4*)((const short*)K + (long)gk1 * D_ + cc1 * 8);
        }
        if (tid < 32) {
            int key2 = t0 * 32 + tid;
            pv = (key2 < S_) ? vl[b * S_ + key2] : 0.f;
        }
    }

    for (int k = 0; k < nit; ++k) {
        int it = t0 + k;
        int buf = k & 1;
        *(uint4*)&s_k[buf][row0 * 200 + cc0 * 8] = p0;
        if (has1) *(uint4*)&s_k[buf][row1 * 200 + cc1 * 8] = p1;
        if (tid < 32) s_vl[buf][tid] = pv;
        if (k + 1 < nit) {
            int it1 = it + 1;
            int key = it1 * 32 + row0;
            int gk = b * S_ + (key < S_ ? key : S_ - 1);
            p0 = *(const uint4*)((const short*)K + (long)gk * D_ + cc0 * 8);
            if (has1) {
                int key1 = it1 * 32 + row1;
                int gk1 = b * S_ + (key1 < S_ ? key1 : S_ - 1);
                p1 = *(const uint4*)((const short*)K + (long)gk1 * D_ + cc1 * 8);
            }
            if (tid < 32) {
                int key2 = it1 * 32 + tid;
                pv = (key2 < S_) ? vl[b * S_ + key2] : 0.f;
            }
        }
        __syncthreads();
        const short* kb = s_k[buf];
        float16v c;
        #pragma unroll
        for (int r = 0; r < 16; r++) c[r] = 0.f;
        #pragma unroll
        for (int kc = 0; kc < 12; kc++) {
            short8 bfr = *(const short8*)(kb + n5 * 200 + kc * 16 + h5 * 8);
            c = __builtin_amdgcn_mfma_f32_32x32x16_bf16(qf[kc], bfr, c, 0, 0, 0);
        }
        float vlv = s_vl[buf][n5];
        if (it != KITERS - 1) {
            #pragma unroll
            for (int r = 0; r < 16; r++) {
                float p = __builtin_amdgcn_exp2f(c[r]);
                lr[r] += p;
                ar[r] += p * vlv;
            }
        } else {
            bool kv = n5 < 16;
            #pragma unroll
            for (int r = 0; r < 16; r++) {
                float p = kv ? __builtin_amdgcn_exp2f(c[r]) : 0.f;
                lr[r] += p;
                ar[r] += p * vlv;
            }
        }
    }

    if (qvalid) {
        #pragma unroll
        for (int r = 0; r < 16; r++) {
            float l = lr[r], a = ar[r];
            #pragma unroll
            for (int off = 1; off < 32; off <<= 1) {
                l += __shfl_xor(l, off, 64);
                a += __shfl_xor(a, off, 64);
            }
            if (n5 == 0) {
                int qrow = qt * 32 + (r & 3) + 8 * (r >> 2) + 4 * h5;
                if (qrow < S_) {
                    float2v pv2 = {l, a};
                    *(float2v*)&part[((long)(b * S_ + qrow) * 8 + chunk) * 2] = pv2;
                }
            }
        }
    }
}

// ============ K5: merge partials + pairing/argmin ============
__global__ __launch_bounds__(256) void final_kernel(const float* part, const float* sc,
                                                    float* out) {
    int idx = blockIdx.x * 256 + threadIdx.x;
    if (idx >= B_ * SH) return;
    int b = idx / SH, p = idx % SH;
    int i = (int)((1.0f + sqrtf(8.0f * (float)p + 1.0f)) * 0.5f);
    while (i * (i - 1) / 2 > p) --i;
    while ((i + 1) * i / 2 <= p) ++i;
    int j = p - i * (i - 1) / 2;
    float co = sc[1];
    float lg[2];
    #pragma unroll
    for (int t = 0; t < 2; t++) {
        long g = (long)b * S_ + 2 * p + t;
        float l = 0.f, a = 0.f;
        #pragma unroll
        for (int c = 0; c < 8; c++) {
            float2v pc = *(const float2v*)&part[(g * 8 + c) * 2];
            l += pc.x;
            a += pc.y;
        }
        lg[t] = sanitize(a / l + co);
    }
    int ind = (lg[1] < lg[0]) ? 1 : 0;
    float ef = ind ? lg[1] : lg[0];
    out[(b * SH + p) * 2 + 0] = (float)(b * N_ + i);
    out[(b * SH + p) * 2 + 1] = (float)(b * N_ + j);
    out[2 * B_ * SH + idx] = ef;
    out[2 * B_ * SH + B_ * SH + idx] = (float)ind;
}

extern "C" void kernel_launch(void* const* d_in, const int* in_sizes, int n_in,
                              void* d_out, int out_size, void* d_ws, size_t ws_size,
                              hipStream_t stream) {
    const bf16* x         = (const bf16*)d_in[0];
    const bf16* edge_attr = (const bf16*)d_in[2];
    const bf16* W_we   = (const bf16*)d_in[5];
    const bf16* b_we   = (const bf16*)d_in[6];
    const bf16* Wrel1  = (const bf16*)d_in[7];
    const bf16* brel1  = (const bf16*)d_in[8];
    const bf16* Wroot1 = (const bf16*)d_in[9];
    const bf16* Wrel2  = (const bf16*)d_in[10];
    const bf16* brel2  = (const bf16*)d_in[11];
    const bf16* Wroot2 = (const bf16*)d_in[12];
    const bf16* W_ee   = (const bf16*)d_in[13];
    const bf16* b_ee   = (const bf16*)d_in[14];
    const bf16* W_qkv  = (const bf16*)d_in[15];
    const bf16* b_qkv  = (const bf16*)d_in[16];
    const bf16* W_in   = (const bf16*)d_in[17];
    const bf16* b_in   = (const bf16*)d_in[18];
    const bf16* W_out  = (const bf16*)d_in[19];
    const bf16* b_out  = (const bf16*)d_in[20];
    const bf16* W_o    = (const bf16*)d_in[21];
    const bf16* b_o    = (const bf16*)d_in[22];

    float* w = (float*)d_ws;
    float* WqT    = w;                  // 36864
    float* WkT    = WqT + 36864;        // 36864
    float* bq_eff = WkT + 36864;        // 192
    float* bk_eff = bq_eff + 192;
    float* bv_eff = bk_eff + 192;
    float* wo_eff = bv_eff + 192;
    float* wvl    = wo_eff + 192;       // 192
    float* sc     = wvl + 192;          // 64 (2 used)
    float* x2     = sc + 64;            // 49152
    float* vl     = x2 + 49152;         // 36096
    float* part   = vl + 36096;         // 577536
    bf16*  Q      = (bf16*)(part + 577536);   // EK*192 bf16
    bf16*  K      = Q + (long)EK * D_;        // EK*192 bf16
    bf16*  W2b    = K + (long)EK * D_;        // 384*64 bf16
    float* Tq1    = (float*)(W2b + 384 * 64);
    float* Tq3    = Tq1 + NODES * D_;
    float* Tk1    = Tq3 + NODES * D_;
    float* Tk3    = Tk1 + NODES * D_;
    // total ~36 MB of 256 MB workspace

    stage1_kernel<<<497, 256, 0, stream>>>(edge_attr, W_we, b_we, x, Wrel1, brel1, Wroot1,
                                           Wrel2, brel2, Wroot2, W_o, b_o, W_out, b_out,
                                           W_in, b_in, b_qkv, W_qkv,
                                           x2, wo_eff, bq_eff, bk_eff, bv_eff, sc,
                                           WqT, WkT, W2b);
    stage2_kernel<<<961, 256, 0, stream>>>(W_in, W_qkv, wo_eff, bv_eff, x2, WqT, WkT,
                                           bq_eff, bk_eff, wvl, sc, Tq1, Tq3, Tk1, Tk3);
    qkvmid_kernel<<<EK / 32, 256, 0, stream>>>(edge_attr, W_ee, b_ee, W2b, wvl, sc, x2,
                                               Tq1, Tq3, Tk1, Tk3, Q, K, vl);
    attn_kernel<<<1152, 512, 0, stream>>>(Q, K, vl, part);
    final_kernel<<<(B_ * SH + 255) / 256, 256, 0, stream>>>(part, sc, (float*)d_out);
}